// Round 11
// baseline (121.430 us; speedup 1.0000x reference)
//
#include <hip/hip_runtime.h>
#include <hip/hip_bf16.h>

#define B_TOT 16384
#define C_CH  64
#define F_IN  128
#define H_HID 128
#define CG    8            // channels per block (4KB contiguous per row-chunk)
#define TROWS 16           // batch rows per tile; one row per wave
#define NSUB  32           // tiles per block -> 512 rows
#define ROWS  (NSUB * TROWS)

using f32x4  = __attribute__((ext_vector_type(4))) float;
using bf16x8 = __attribute__((ext_vector_type(8))) short;

__device__ inline unsigned pack2(float a, float b) {
    unsigned short lo = __builtin_bit_cast(unsigned short, __float2bfloat16(a));
    unsigned short hi = __builtin_bit_cast(unsigned short, __float2bfloat16(b));
    return (unsigned)lo | ((unsigned)hi << 16);
}

// async global->LDS, 16B/lane; LDS dest = wave-uniform base + lane*16 (HW rule)
__device__ inline void gld_lds16(const float* g, float* l) {
    __builtin_amdgcn_global_load_lds(
        (const __attribute__((address_space(1))) void*)g,
        (__attribute__((address_space(3))) void*)l, 16, 0, 0);
}

// Stage tile: each of 16 waves stages ONE row-chunk X[r, c0..c0+8, :] = 4KB
// CONTIGUOUS (the contiguity lever, now 4KB/visit). 4 instrs x 1KB each.
// Source-side XOR swizzle (lane ^ (r&7)) within each 1KB chunk so the
// ds_read_b128 consume side is at the structural bank floor.
// LDS: float off = r*1024 + h*256 + lane*4 holds global unit lane^sw of chunk h.
__device__ inline void issue_tile(const float* __restrict__ X, size_t base0,
                                  int wave, int lane, float* buf) {
    const float* rowp = X + base0 + (size_t)wave * (C_CH * F_IN);
    const int sw = wave & 7;
    float* dst = buf + wave * 1024;
    #pragma unroll
    for (int h = 0; h < 4; ++h)
        gld_lds16(rowp + h * 256 + ((lane ^ sw) << 2), dst + h * 256);
}

__global__ __launch_bounds__(1024, 4)   // 16 waves, 4/SIMD -> VGPR cap 128
void fused_mlp_kernel(const float* __restrict__ X,
                      const float* __restrict__ W1,
                      const float* __restrict__ b1,
                      const float* __restrict__ W2,
                      const float* __restrict__ b2,
                      float* __restrict__ out)
{
    __shared__ alignas(16) float Xs[2 * TROWS * 1024];  // 2 x 64KB X tiles
    __shared__ alignas(16) float w2t[CG * H_HID];       // 4KB W2 table
    __shared__ alignas(16) float b1t[CG * H_HID];       // 4KB b1 table

    const int t    = threadIdx.x;
    const int lane = t & 63;
    const int wave = t >> 6;            // 16 waves: role = (ch, h-half)
    const int l15  = lane & 15;
    const int lg   = lane >> 4;
    const int ch   = wave & 7;
    const int hh   = wave >> 3;

    const int c0 = blockIdx.x * CG;
    const int c  = c0 + ch;
    const int m0 = blockIdx.y * ROWS;

    float* bu0 = Xs;
    float* bu1 = Xs + TROWS * 1024;

    // prefill both buffers first: HBM latency hides under W-reg staging
    const size_t cbase = ((size_t)m0 * C_CH + c0) * F_IN;
    const size_t tstep = (size_t)TROWS * C_CH * F_IN;
    issue_tile(X, cbase, wave, lane, bu0);
    issue_tile(X, cbase + tstep, wave, lane, bu1);

    // w2/b1 tables -> LDS (saves 48 resident VGPR vs r9's register copies)
    w2t[t] = W2[c0 * H_HID + t];        // 8ch x 128h = 1024 floats, coalesced
    b1t[t] = b1[c0 * H_HID + t];

    // ---- W1 fragments -> registers (64 VGPR): wave owns (channel, h-half) ----
    bf16x8 wf[4][4];
    {
        const float* wb = W1 + (size_t)c * F_IN * H_HID + hh * 64 + l15;
        #pragma unroll
        for (int nf = 0; nf < 4; ++nf)
            #pragma unroll
            for (int ks = 0; ks < 4; ++ks) {
                const int f0 = ks * 32 + lg * 8;
                float v[8];
                #pragma unroll
                for (int e = 0; e < 8; ++e)
                    v[e] = wb[(size_t)(f0 + e) * H_HID + nf * 16];
                uint4 p;
                p.x = pack2(v[0], v[1]);
                p.y = pack2(v[2], v[3]);
                p.z = pack2(v[4], v[5]);
                p.w = pack2(v[6], v[7]);
                wf[nf][ks] = __builtin_bit_cast(bf16x8, p);
            }
    }
    const float b2c = (hh == 0) ? b2[c] : 0.f;   // b2[c] added once per channel

    // ---- main loop: counted vmcnt + barrier per round, 2-buf rotation ----
    // vm ops/round/wave: 4 gld_lds then 1 atomic (youngest). Tile sc retired
    // <=> vmcnt <= 1 (allows the prior atomic to stay outstanding). Never 0.
    #pragma unroll 1
    for (int sc = 0; sc < NSUB; ++sc) {
        asm volatile("s_waitcnt vmcnt(1)" ::: "memory");
        __builtin_amdgcn_s_barrier();      // all 16 waves' rows in; prev reads done
        asm volatile("" ::: "memory");

        const float* xb = (sc & 1) ? bu1 : bu0;
        float*       nb = (sc & 1) ? bu0 : bu1;
        if (sc + 1 < NSUB)
            issue_tile(X, cbase + (size_t)(sc + 1) * tstep, wave, lane, nb);

        // ---- 16 MFMA: W(regs) as A, X(LDS) as B => batch row lane-local ----
        f32x4 acc[4];
        #pragma unroll
        for (int nf = 0; nf < 4; ++nf) acc[nf] = f32x4{0.f, 0.f, 0.f, 0.f};

        const int sw = l15 & 7;            // row l15 staged by wave l15
        const int rb = l15 * 1024 + (ch >> 1) * 256;
        #pragma unroll
        for (int ks = 0; ks < 4; ++ks) {
            const int u = (ch & 1) * 32 + ks * 8 + lg * 2;
            float4 r0 = *reinterpret_cast<const float4*>(xb + rb + ((u ^ sw) << 2));
            float4 r1 = *reinterpret_cast<const float4*>(xb + rb + (((u + 1) ^ sw) << 2));
            uint4 px;
            px.x = pack2(r0.x, r0.y);
            px.y = pack2(r0.z, r0.w);
            px.z = pack2(r1.x, r1.y);
            px.w = pack2(r1.z, r1.w);
            bf16x8 xfrag = __builtin_bit_cast(bf16x8, px);
            #pragma unroll
            for (int nf = 0; nf < 4; ++nf)
                acc[nf] = __builtin_amdgcn_mfma_f32_16x16x32_bf16(
                    wf[nf][ks], xfrag, acc[nf], 0, 0, 0);
        }

        // ---- epilogue: relu(+b1) dot W2 from LDS tables (transient regs),
        //      2 shuffles, one 16-lane atomic ----
        float val = 0.f;
        #pragma unroll
        for (int nf = 0; nf < 4; ++nf) {
            const int ho = ch * H_HID + hh * 64 + nf * 16 + lg * 4;
            f32x4 w2c = *reinterpret_cast<const f32x4*>(&w2t[ho]);  // broadcast
            f32x4 b1c = *reinterpret_cast<const f32x4*>(&b1t[ho]);
            #pragma unroll
            for (int j = 0; j < 4; ++j)
                val += fmaxf(acc[nf][j] + b1c[j], 0.f) * w2c[j];
        }
        val += __shfl_xor(val, 16, 64);    // sum the 4 lg-groups (h quarters)
        val += __shfl_xor(val, 32, 64);
        if (lane < 16) atomicAdd(&out[m0 + sc * TROWS + lane], val + b2c);
    }
}

extern "C" void kernel_launch(void* const* d_in, const int* in_sizes, int n_in,
                              void* d_out, int out_size, void* d_ws, size_t ws_size,
                              hipStream_t stream) {
    const float* X  = (const float*)d_in[0];   // [B, C, F]
    const float* W1 = (const float*)d_in[1];   // [C, F, H]
    const float* b1 = (const float*)d_in[2];   // [C, H]
    const float* W2 = (const float*)d_in[3];   // [C, H]
    const float* b2 = (const float*)d_in[4];   // [C]
    float* out = (float*)d_out;                // [B]

    // atomics accumulate into out -> must zero it every call (d_out is poisoned)
    hipMemsetAsync(out, 0, (size_t)out_size * sizeof(float), stream);

    dim3 grid(C_CH / CG, B_TOT / ROWS);   // (8, 32) = 256 blocks = 1/CU
    fused_mlp_kernel<<<grid, dim3(1024), 0, stream>>>(X, W1, b1, W2, b2, out);
}

// Round 12
// 106.354 us; speedup vs baseline: 1.1417x; 1.1417x over previous
//
#include <hip/hip_runtime.h>
#include <hip/hip_bf16.h>

#define B_TOT 16384
#define C_CH  64
#define F_IN  128
#define H_HID 128
#define CG    4            // channels per block (2KB contiguous per row-chunk)
#define TROWS 16           // batch rows per tile
#define NSUB  64           // tiles per block -> 1024 rows
#define ROWS  (NSUB * TROWS)

using f32x4  = __attribute__((ext_vector_type(4))) float;
using bf16x8 = __attribute__((ext_vector_type(8))) short;

__device__ inline unsigned pack2(float a, float b) {
    unsigned short lo = __builtin_bit_cast(unsigned short, __float2bfloat16(a));
    unsigned short hi = __builtin_bit_cast(unsigned short, __float2bfloat16(b));
    return (unsigned)lo | ((unsigned)hi << 16);
}

// async global->LDS, 16B/lane; LDS dest = wave-uniform base + lane*16 (HW rule)
__device__ inline void gld_lds16(const float* g, float* l) {
    __builtin_amdgcn_global_load_lds(
        (const __attribute__((address_space(1))) void*)g,
        (__attribute__((address_space(3))) void*)l, 16, 0, 0);
}

// Stage tile: 16 rows x 2KB (4 adjacent channels = contiguous span; ~HBM page).
// Each instr reads a fully CONTIGUOUS 1KB. Source-side XOR swizzle
// (lane ^ (row&7)) within the 1KB so ds_read_b128 is bank-balanced.
// LDS layout: float off = r*512 + h*256 + lane*4 holds global unit lane^sw.
__device__ inline void issue_tile(const float* __restrict__ X, size_t base0,
                                  int wave, int lane, float* buf) {
    #pragma unroll
    for (int q = 0; q < 2; ++q) {
        const int r = wave * 2 + q;                    // 8 waves x 2 rows = 16
        const float* rowp = X + base0 + (size_t)r * (C_CH * F_IN);
        const int sw = r & 7;
        #pragma unroll
        for (int h = 0; h < 2; ++h)
            gld_lds16(rowp + h * 256 + ((lane ^ sw) << 2),
                      buf + r * 512 + h * 256);
    }
}

// One round: wait own tile retired (counted vmcnt, exact ledger - never 0
// mid-loop), barrier (all waves' slices in; 4-buf rotation makes overwrite
// safe), 16 MFMA with W(regs) as A, X(LDS) as B => batch row lane-local;
// epilogue = in-lane relu-dot + 2 shuffles. b1 rides as MFMA C-init.
template<int N>
__device__ inline float compute_round(const float* __restrict__ xb,
                                      const bf16x8 (&wf)[4][4],
                                      const f32x4 (&w2c)[4],
                                      const f32x4 (&b1c)[4],
                                      int l15, int lg, int ch)
{
    asm volatile("s_waitcnt vmcnt(%0)" :: "i"(N) : "memory");
    __builtin_amdgcn_s_barrier();

    f32x4 acc[4];
    #pragma unroll
    for (int nf = 0; nf < 4; ++nf) acc[nf] = b1c[nf];

    const int sw = l15 & 7;
    const int rb = l15 * 512 + (ch >> 1) * 256;
    #pragma unroll
    for (int ks = 0; ks < 4; ++ks) {
        const int u = (ch & 1) * 32 + ks * 8 + lg * 2;
        float4 r0 = *reinterpret_cast<const float4*>(xb + rb + ((u ^ sw) << 2));
        float4 r1 = *reinterpret_cast<const float4*>(xb + rb + (((u + 1) ^ sw) << 2));
        uint4 px;
        px.x = pack2(r0.x, r0.y);
        px.y = pack2(r0.z, r0.w);
        px.z = pack2(r1.x, r1.y);
        px.w = pack2(r1.z, r1.w);
        bf16x8 xfrag = __builtin_bit_cast(bf16x8, px);
        #pragma unroll
        for (int nf = 0; nf < 4; ++nf)
            acc[nf] = __builtin_amdgcn_mfma_f32_16x16x32_bf16(
                wf[nf][ks], xfrag, acc[nf], 0, 0, 0);
    }

    float val = 0.f;
    #pragma unroll
    for (int nf = 0; nf < 4; ++nf)
        #pragma unroll
        for (int j = 0; j < 4; ++j)
            val += fmaxf(acc[nf][j], 0.f) * w2c[nf][j];
    val += __shfl_xor(val, 16, 64);   // sum the 4 lg-groups (h quarters)
    val += __shfl_xor(val, 32, 64);
    return val;
}

__global__ __launch_bounds__(512, 2)
void fused_mlp_kernel(const float* __restrict__ X,
                      const float* __restrict__ W1,
                      const float* __restrict__ b1,
                      const float* __restrict__ W2,
                      const float* __restrict__ b2,
                      float* __restrict__ out)
{
    __shared__ alignas(16) float Xs[4 * TROWS * 512];   // 4 bufs x 32KB = 128KB

    const int t    = threadIdx.x;
    const int lane = t & 63;
    const int wave = t >> 6;            // 8 waves: role = (ch, h-half)
    const int l15  = lane & 15;
    const int lg   = lane >> 4;
    const int ch   = wave & 3;
    const int hh   = wave >> 2;

    const int c0 = blockIdx.x * CG;
    const int c  = c0 + ch;
    const int m0 = blockIdx.y * ROWS;

    float* bu0 = Xs;
    float* bu1 = Xs + TROWS * 512;
    float* bu2 = Xs + 2 * TROWS * 512;
    float* bu3 = Xs + 3 * TROWS * 512;

    // prefill 3 tiles: depth-3 prefetch (96KB in flight), HBM latency hides
    // under W-reg staging
    const size_t cbase = ((size_t)m0 * C_CH + c0) * F_IN;
    const size_t tstep = (size_t)TROWS * C_CH * F_IN;
    issue_tile(X, cbase, wave, lane, bu0);
    issue_tile(X, cbase + tstep, wave, lane, bu1);
    issue_tile(X, cbase + 2 * tstep, wave, lane, bu2);

    // ---- W1 fragments -> registers (64 VGPR): wave owns (channel, h-half) ----
    bf16x8 wf[4][4];
    {
        const float* wb = W1 + (size_t)c * F_IN * H_HID + hh * 64 + l15;
        #pragma unroll
        for (int nf = 0; nf < 4; ++nf)
            #pragma unroll
            for (int ks = 0; ks < 4; ++ks) {
                const int f0 = ks * 32 + lg * 8;
                float v[8];
                #pragma unroll
                for (int e = 0; e < 8; ++e)
                    v[e] = wb[(size_t)(f0 + e) * H_HID + nf * 16];
                uint4 p;
                p.x = pack2(v[0], v[1]);
                p.y = pack2(v[2], v[3]);
                p.z = pack2(v[4], v[5]);
                p.w = pack2(v[6], v[7]);
                wf[nf][ks] = __builtin_bit_cast(bf16x8, p);
            }
    }
    f32x4 w2c[4], b1c[4];
    #pragma unroll
    for (int nf = 0; nf < 4; ++nf) {
        const int ho = c * H_HID + hh * 64 + nf * 16 + lg * 4;
        w2c[nf] = *reinterpret_cast<const f32x4*>(W2 + ho);
        b1c[nf] = *reinterpret_cast<const f32x4*>(b1 + ho);
    }
    const float b2c = (hh == 0) ? b2[c] : 0.f;   // b2[c] added once per channel

    // ---- vmcnt ledger (per wave, in-order decrement) ----
    // prefill = 12 loads; each full round appends [4 loads (sc+3), 1 atomic].
    // younger-than-tile-sc at wait(sc): sc=0:8, sc=1:9, sc=2:10, 3..61:11,
    // 62:7, 63:3. Exact peel; N too big races, too small over-syncs.
    #define DO_ROUND(NWAIT, SC, ISSUE)                                          \
        {                                                                       \
            float val = compute_round<NWAIT>(bu0, wf, w2c, b1c, l15, lg, ch);   \
            if (ISSUE)                                                          \
                issue_tile(X, cbase + (size_t)((SC) + 3) * tstep, wave, lane, bu3); \
            if (lane < 16) atomicAdd(&out[m0 + (SC) * TROWS + lane], val + b2c); \
            float* tmp = bu0; bu0 = bu1; bu1 = bu2; bu2 = bu3; bu3 = tmp;       \
        }

    DO_ROUND(8, 0, true)
    DO_ROUND(9, 1, true)
    DO_ROUND(10, 2, true)
    #pragma unroll 1
    for (int sc = 3; sc <= 61; ++sc)
        DO_ROUND(11, sc, (sc + 3 < NSUB))
    DO_ROUND(7, 62, false)
    DO_ROUND(3, 63, false)
    #undef DO_ROUND
}

extern "C" void kernel_launch(void* const* d_in, const int* in_sizes, int n_in,
                              void* d_out, int out_size, void* d_ws, size_t ws_size,
                              hipStream_t stream) {
    const float* X  = (const float*)d_in[0];   // [B, C, F]
    const float* W1 = (const float*)d_in[1];   // [C, F, H]
    const float* b1 = (const float*)d_in[2];   // [C, H]
    const float* W2 = (const float*)d_in[3];   // [C, H]
    const float* b2 = (const float*)d_in[4];   // [C]
    float* out = (float*)d_out;                // [B]

    // atomics accumulate into out -> must zero it every call (d_out is poisoned)
    hipMemsetAsync(out, 0, (size_t)out_size * sizeof(float), stream);

    dim3 grid(C_CH / CG, B_TOT / ROWS);   // (16, 16) = 256 blocks = 1/CU
    fused_mlp_kernel<<<grid, dim3(512), 0, stream>>>(X, W1, b1, W2, b2, out);
}